// Round 11
// baseline (19.481 us; speedup 1.0000x reference)
//
#include <hip/hip_runtime.h>
#include <math.h>
#include <float.h>

// Problem constants (fixed by setup_inputs):
//   outputs: [8, 512, 12]  targets: [8, 512, 1, 2, 128]
//   W_dec: [12, 256]       b_dec: [256]      out: scalar fp32
#define NCOMP 12
#define NS 128
#define NBS 4096   // 8 * 512

typedef float f32x2 __attribute__((ext_vector_type(2)));
typedef float f32x4 __attribute__((ext_vector_type(4)));

__device__ __forceinline__ f32x4 shfl_xor4(f32x4 v, int mask) {
    f32x4 r;
    r.x = __shfl_xor(v.x, mask);
    r.y = __shfl_xor(v.y, mask);
    r.z = __shfl_xor(v.z, mask);
    r.w = __shfl_xor(v.w, mask);
    return r;
}

// Block = 4 waves = 2 bsq; each bsq gets TWO waves (sub 0/1), each scanning
// half the candidate pairs. 2048 blocks -> 8192 waves = 8 waves/SIMD (max
// occupancy at <=64 VGPR) to hide ds_read + VALU-chain latency.
__global__ __launch_bounds__(256, 8)
void p2cp_wave_kernel(const float* __restrict__ outputs,
                      const float* __restrict__ targets,
                      const float* __restrict__ W_dec,
                      const float* __restrict__ b_dec,
                      float* __restrict__ partial) {
    const int wav  = threadIdx.x >> 6;      // 0..3
    const int sub  = wav & 1;               // candidate-half this wave scans
    const int slot = wav >> 1;              // which of the block's 2 bsq
    const int lane = threadIdx.x & 63;
    const int bsq  = blockIdx.x * 2 + slot;

    // Per-bsq LDS: c4[side][pair] = {x_{2m}, x_{2m+1}, y_{2m}, y_{2m+1}}.
    // Both sub-waves write the FULL array (identical values) -> each wave's
    // reads are satisfied by its own writes: no pre-scan barrier needed.
    __shared__ __align__(16) f32x4 c4s[2][2][NS / 2];
    __shared__ __align__(16) f32x4 comb[2][64];       // sub1 -> sub0 min handoff
    f32x4 (*c4)[NS / 2] = c4s[slot];

    const int half = lane >> 5;   // 0: x-carrier (owns u-points), 1: y-carrier (owns v)
    const int m    = lane & 31;   // carries one coord of points 4m..4m+3

    // ---- o coefficients (12 floats, uniform within wave) ----
    const float* ob = outputs + (size_t)bsq * NCOMP;
    const f32x4 o0 = *reinterpret_cast<const f32x4*>(ob);
    const f32x4 o1 = *reinterpret_cast<const f32x4*>(ob + 4);
    const f32x4 o2 = *reinterpret_cast<const f32x4*>(ob + 8);

    // ---- decode shape elements 4*lane..4*lane+3 ----
    f32x4 du = *reinterpret_cast<const f32x4*>(b_dec + 4 * lane);
    const float* wb = W_dec + 4 * lane;
    #pragma unroll
    for (int k = 0; k < 4; ++k)
        du += o0[k] * *reinterpret_cast<const f32x4*>(wb + (k    ) * 256);
    #pragma unroll
    for (int k = 0; k < 4; ++k)
        du += o1[k] * *reinterpret_cast<const f32x4*>(wb + (k + 4) * 256);
    #pragma unroll
    for (int k = 0; k < 4; ++k)
        du += o2[k] * *reinterpret_cast<const f32x4*>(wb + (k + 8) * 256);

    // ---- target coords, same split: lanes<32 x_v, lanes>=32 y_v ----
    const float* tb = targets + (size_t)bsq * (2 * NS);
    const f32x4 dv = *reinterpret_cast<const f32x4*>(tb + 4 * lane);

    // ---- partner exchange: complete own points in registers ----
    const f32x4 pu = shfl_xor4(du, 32);
    const f32x4 pv = shfl_xor4(dv, 32);
    const f32x4 ox = half ? pv : du;
    const f32x4 oy = half ? dv : pu;
    f32x4 zz4;
    #pragma unroll
    for (int c = 0; c < 4; ++c) zz4[c] = fmaf(ox[c], ox[c], oy[c] * oy[c]);

    // ---- pack candidates to LDS (full array per wave, R10 layout) ----
    {
        float* u0 = reinterpret_cast<float*>(&c4[0][2 * m])     + 2 * half;
        float* u1 = reinterpret_cast<float*>(&c4[0][2 * m + 1]) + 2 * half;
        float* v0 = reinterpret_cast<float*>(&c4[1][2 * m])     + 2 * half;
        float* v1 = reinterpret_cast<float*>(&c4[1][2 * m + 1]) + 2 * half;
        *reinterpret_cast<f32x2*>(u0) = f32x2{du.x, du.y};
        *reinterpret_cast<f32x2*>(u1) = f32x2{du.z, du.w};
        *reinterpret_cast<f32x2*>(v0) = f32x2{dv.x, dv.y};
        *reinterpret_cast<f32x2*>(v1) = f32x2{dv.z, dv.w};
    }
    // Wave-synchronous publish: this wave reads only what it wrote itself.
    asm volatile("s_waitcnt lgkmcnt(0)" ::: "memory");
    __builtin_amdgcn_sched_barrier(0);

    // ---- scan: own 4 points vs HALF the opposite-side pairs ----
    const f32x4* cp = c4[1 - half] + sub * 32;

    f32x2 ab[4];
    float mn[4];
    #pragma unroll
    for (int k = 0; k < 4; ++k) {
        ab[k] = f32x2{-2.0f * ox[k], -2.0f * oy[k]};
        mn[k] = FLT_MAX;
    }

    #pragma unroll 8
    for (int i = 0; i < 32; ++i) {
        const f32x4 q = cp[i];                     // {x0,x1,y0,y1} broadcast
        f32x2 xx; xx.x = q.x; xx.y = q.y;
        f32x2 yy; yy.x = q.z; yy.y = q.w;
        const f32x2 z2 = xx * xx + yy * yy;        // candidate |q|^2 on the fly
        #pragma unroll
        for (int k = 0; k < 4; ++k) {
            f32x2 t1, dd;
            asm("v_pk_fma_f32 %0, %1, %2, %3 op_sel:[1,0,0] op_sel_hi:[1,1,1]"
                : "=v"(t1) : "v"(ab[k]), "v"(yy), "v"(z2));   // {b*y0+z0, b*y1+z1}
            asm("v_pk_fma_f32 %0, %1, %2, %3 op_sel:[0,0,0] op_sel_hi:[0,1,1]"
                : "=v"(dd) : "v"(ab[k]), "v"(xx), "v"(t1));   // {a*x0+., a*x1+.}
            asm("v_min3_f32 %0, %1, %2, %3"
                : "=v"(mn[k]) : "v"(mn[k]), "v"(dd.x), "v"(dd.y));
        }
    }

    // ---- cross-wave min combine (sub1 -> sub0), then finalize on sub0 ----
    if (sub == 1)
        comb[slot][lane] = f32x4{mn[0], mn[1], mn[2], mn[3]};
    __syncthreads();
    if (sub == 0) {
        const f32x4 o2m = comb[slot][lane];
        float s = 0.0f;
        #pragma unroll
        for (int k = 0; k < 4; ++k) {
            const float mk = fminf(mn[k], o2m[k]);
            const float d2 = fmaxf(mk + zz4[k], 0.0f);   // matches jnp.maximum(d2,0)
            s += sqrtf(d2 + 1e-12f);                     // sqrt after min (monotone)
        }
        #pragma unroll
        for (int off = 32; off > 0; off >>= 1)
            s += __shfl_xor(s, off);
        if (lane == 0)
            partial[bsq] = s;   // sum of 256 per-point min-distances for this (b,s)
    }
}

__global__ __launch_bounds__(256)
void final_reduce_kernel(const float* __restrict__ partial,
                         float* __restrict__ out) {
    const int t = threadIdx.x;
    const f32x4* p4 = reinterpret_cast<const f32x4*>(partial);
    f32x4 acc = f32x4{0.0f, 0.0f, 0.0f, 0.0f};
    #pragma unroll
    for (int i = 0; i < 4; ++i) acc += p4[t + 256 * i];
    float s = (acc.x + acc.y) + (acc.z + acc.w);
    #pragma unroll
    for (int off = 32; off > 0; off >>= 1)
        s += __shfl_down(s, off);
    __shared__ float red[4];
    const int lane = t & 63;
    const int wid  = t >> 6;
    if (lane == 0) red[wid] = s;
    __syncthreads();
    if (t == 0) {
        const float total = red[0] + red[1] + red[2] + red[3];
        // per-(b,s): 0.5*(u2v.mean+v2u.mean) = wavesum/256; then mean over 4096
        out[0] = total * (1.0f / (256.0f * (float)NBS));
    }
}

extern "C" void kernel_launch(void* const* d_in, const int* in_sizes, int n_in,
                              void* d_out, int out_size, void* d_ws, size_t ws_size,
                              hipStream_t stream) {
    const float* outputs = (const float*)d_in[0];
    const float* targets = (const float*)d_in[1];
    const float* W_dec   = (const float*)d_in[2];
    const float* b_dec   = (const float*)d_in[3];
    float* out = (float*)d_out;
    float* ws  = (float*)d_ws;   // 4096 floats = 16 KB of partials

    p2cp_wave_kernel<<<NBS / 2, 256, 0, stream>>>(outputs, targets, W_dec, b_dec, ws);
    final_reduce_kernel<<<1, 256, 0, stream>>>(ws, out);
}

// Round 12
// 17.485 us; speedup vs baseline: 1.1141x; 1.1141x over previous
//
#include <hip/hip_runtime.h>
#include <math.h>
#include <float.h>

// Problem constants (fixed by setup_inputs):
//   outputs: [8, 512, 12]  targets: [8, 512, 1, 2, 128]
//   W_dec: [12, 256]       b_dec: [256]      out: scalar fp32
//
// Structure (best measured config, R8 = 17.30 us):
//   kernel1: one 64-lane wave per (b,s); decode u in registers, exchange
//            halves via shfl_xor(32) so each lane owns 4 complete points;
//            candidates pair-packed in per-wave LDS ({x0,x1,y0,y1} + |q|^2);
//            scan all 64 opposite-side pairs with v_pk_fma_f32 + v_min3_f32;
//            zero __syncthreads (wave-synchronous LDS, one lgkmcnt drain).
//   kernel2: single-block deterministic sum of the 4096 partials.
// Fusion into one dispatch was tried (R6) and is 6x SLOWER: cross-block
// visibility requires coherent-point RMWs whose cost dwarfs a launch.
#define NCOMP 12
#define NS 128
#define NBS 4096   // 8 * 512
#define WPB 4      // waves per block (one bsq per wave)

typedef float f32x2 __attribute__((ext_vector_type(2)));
typedef float f32x4 __attribute__((ext_vector_type(4)));

__device__ __forceinline__ f32x4 shfl_xor4(f32x4 v, int mask) {
    f32x4 r;
    r.x = __shfl_xor(v.x, mask);
    r.y = __shfl_xor(v.y, mask);
    r.z = __shfl_xor(v.z, mask);
    r.w = __shfl_xor(v.w, mask);
    return r;
}

__global__ __launch_bounds__(256)
void p2cp_wave_kernel(const float* __restrict__ outputs,
                      const float* __restrict__ targets,
                      const float* __restrict__ W_dec,
                      const float* __restrict__ b_dec,
                      float* __restrict__ partial) {
    const int wav  = threadIdx.x >> 6;            // wave in block: 0..3
    const int lane = threadIdx.x & 63;
    const int bsq  = blockIdx.x * WPB + wav;      // one (b,s) per wave

    // Per-wave LDS: c4[side][pair] = {x_{2m}, x_{2m+1}, y_{2m}, y_{2m+1}};
    // zz[side][i] = |p_i|^2. side 0 = u (decoded), side 1 = v (targets).
    __shared__ __align__(16) f32x4 c4s[WPB][2][NS / 2];
    __shared__ __align__(16) float zzs[WPB][2][NS];
    f32x4 (*c4)[NS / 2] = c4s[wav];
    float (*zw)[NS]     = zzs[wav];

    const int half = lane >> 5;   // 0: x-carrier (owns u-points), 1: y-carrier (owns v)
    const int m    = lane & 31;   // carries one coord of points 4m..4m+3

    // ---- o coefficients (12 floats, uniform within wave) ----
    const float* ob = outputs + (size_t)bsq * NCOMP;
    const f32x4 o0 = *reinterpret_cast<const f32x4*>(ob);
    const f32x4 o1 = *reinterpret_cast<const f32x4*>(ob + 4);
    const f32x4 o2 = *reinterpret_cast<const f32x4*>(ob + 8);

    // ---- decode shape elements 4*lane..4*lane+3 ----
    // lanes 0..31: x_u of points 4m..4m+3; lanes 32..63: y_u of points 4m..4m+3
    f32x4 du = *reinterpret_cast<const f32x4*>(b_dec + 4 * lane);
    const float* wb = W_dec + 4 * lane;
    #pragma unroll
    for (int k = 0; k < 4; ++k)
        du += o0[k] * *reinterpret_cast<const f32x4*>(wb + (k    ) * 256);
    #pragma unroll
    for (int k = 0; k < 4; ++k)
        du += o1[k] * *reinterpret_cast<const f32x4*>(wb + (k + 4) * 256);
    #pragma unroll
    for (int k = 0; k < 4; ++k)
        du += o2[k] * *reinterpret_cast<const f32x4*>(wb + (k + 8) * 256);

    // ---- target coords, same split: lanes<32 x_v, lanes>=32 y_v ----
    const float* tb = targets + (size_t)bsq * (2 * NS);
    const f32x4 dv = *reinterpret_cast<const f32x4*>(tb + 4 * lane);

    // ---- partner exchange: complete own points in registers ----
    const f32x4 pu = shfl_xor4(du, 32);
    const f32x4 pv = shfl_xor4(dv, 32);
    // x-lane: own u-points, x = du, y = pu.   y-lane: own v-points, x = pv, y = dv.
    const f32x4 ox = half ? pv : du;
    const f32x4 oy = half ? dv : pu;
    f32x4 zz4;
    #pragma unroll
    for (int c = 0; c < 4; ++c) zz4[c] = fmaf(ox[c], ox[c], oy[c] * oy[c]);

    // ---- pack candidates to LDS ----
    {
        float* u0 = reinterpret_cast<float*>(&c4[0][2 * m])     + 2 * half;
        float* u1 = reinterpret_cast<float*>(&c4[0][2 * m + 1]) + 2 * half;
        float* v0 = reinterpret_cast<float*>(&c4[1][2 * m])     + 2 * half;
        float* v1 = reinterpret_cast<float*>(&c4[1][2 * m + 1]) + 2 * half;
        *reinterpret_cast<f32x2*>(u0) = f32x2{du.x, du.y};
        *reinterpret_cast<f32x2*>(u1) = f32x2{du.z, du.w};
        *reinterpret_cast<f32x2*>(v0) = f32x2{dv.x, dv.y};
        *reinterpret_cast<f32x2*>(v1) = f32x2{dv.z, dv.w};
        *reinterpret_cast<f32x4*>(&zw[half][4 * m]) = zz4;  // x-lanes: zz_u, y-lanes: zz_v
    }
    // Wave-synchronous: one LDS drain, NO barrier (per-wave region).
    asm volatile("s_waitcnt lgkmcnt(0)" ::: "memory");
    __builtin_amdgcn_sched_barrier(0);

    // ---- main scan: own 4 points vs all 64 opposite-side pairs ----
    const f32x4* cp = c4[1 - half];
    const float* zp = zw[1 - half];

    f32x2 ab[4];
    float mn[4];
    #pragma unroll
    for (int k = 0; k < 4; ++k) {
        ab[k] = f32x2{-2.0f * ox[k], -2.0f * oy[k]};
        mn[k] = FLT_MAX;
    }

    #pragma unroll 8
    for (int i = 0; i < NS / 2; ++i) {
        const f32x4 q  = cp[i];                                   // {x0,x1,y0,y1} broadcast
        const f32x2 z2 = *reinterpret_cast<const f32x2*>(zp + 2 * i);
        f32x2 xx; xx.x = q.x; xx.y = q.y;
        f32x2 yy; yy.x = q.z; yy.y = q.w;
        #pragma unroll
        for (int k = 0; k < 4; ++k) {
            f32x2 t1, dd;
            asm("v_pk_fma_f32 %0, %1, %2, %3 op_sel:[1,0,0] op_sel_hi:[1,1,1]"
                : "=v"(t1) : "v"(ab[k]), "v"(yy), "v"(z2));   // {b*y0+z0, b*y1+z1}
            asm("v_pk_fma_f32 %0, %1, %2, %3 op_sel:[0,0,0] op_sel_hi:[0,1,1]"
                : "=v"(dd) : "v"(ab[k]), "v"(xx), "v"(t1));   // {a*x0+., a*x1+.}
            asm("v_min3_f32 %0, %1, %2, %3"
                : "=v"(mn[k]) : "v"(mn[k]), "v"(dd.x), "v"(dd.y));
        }
    }

    // ---- finalize own 4 points, wave-sum, store ----
    float s = 0.0f;
    #pragma unroll
    for (int k = 0; k < 4; ++k) {
        const float d2 = fmaxf(mn[k] + zz4[k], 0.0f);  // matches jnp.maximum(d2,0)
        s += sqrtf(d2 + 1e-12f);                       // sqrt monotone: sqrt after min
    }
    #pragma unroll
    for (int off = 32; off > 0; off >>= 1)
        s += __shfl_xor(s, off);
    if (lane == 0)
        partial[bsq] = s;   // sum of 256 per-point min-distances for this (b,s)
}

__global__ __launch_bounds__(256)
void final_reduce_kernel(const float* __restrict__ partial,
                         float* __restrict__ out) {
    const int t = threadIdx.x;
    float s = 0.0f;
    #pragma unroll
    for (int i = 0; i < 16; ++i) s += partial[t + 256 * i];
    #pragma unroll
    for (int off = 32; off > 0; off >>= 1)
        s += __shfl_down(s, off);
    __shared__ float red[4];
    const int lane = t & 63;
    const int wid  = t >> 6;
    if (lane == 0) red[wid] = s;
    __syncthreads();
    if (t == 0) {
        const float total = red[0] + red[1] + red[2] + red[3];
        // per-(b,s): 0.5*(u2v.mean+v2u.mean) = wavesum/256; then mean over 4096
        out[0] = total * (1.0f / (256.0f * (float)NBS));
    }
}

extern "C" void kernel_launch(void* const* d_in, const int* in_sizes, int n_in,
                              void* d_out, int out_size, void* d_ws, size_t ws_size,
                              hipStream_t stream) {
    const float* outputs = (const float*)d_in[0];
    const float* targets = (const float*)d_in[1];
    const float* W_dec   = (const float*)d_in[2];
    const float* b_dec   = (const float*)d_in[3];
    float* out = (float*)d_out;
    float* ws  = (float*)d_ws;   // 4096 floats = 16 KB of partials

    p2cp_wave_kernel<<<NBS / WPB, 256, 0, stream>>>(outputs, targets, W_dec, b_dec, ws);
    final_reduce_kernel<<<1, 256, 0, stream>>>(ws, out);
}